// Round 1
// 476.572 us; speedup vs baseline: 1.1193x; 1.1193x over previous
//
#include <hip/hip_runtime.h>

#define NT   8192
#define DD   2048
#define HH   1408
#define NE   8
#define CAPT 1024

typedef __bf16 bf16x8 __attribute__((ext_vector_type(8)));
typedef float  f32x4  __attribute__((ext_vector_type(4)));
typedef unsigned short us8 __attribute__((ext_vector_type(8)));

#define MFMA16(a, b, c) __builtin_amdgcn_mfma_f32_16x16x32_bf16((a), (b), (c), 0, 0, 0)

__device__ __forceinline__ unsigned short f2bf(float f) {
  union { float f; unsigned u; } v; v.f = f;
  unsigned r = v.u + 0x7fffu + ((v.u >> 16) & 1u);
  return (unsigned short)(r >> 16);
}

__device__ __forceinline__ void load_lds16(const void* g, void* l) {
  __builtin_amdgcn_global_load_lds(
      (const __attribute__((address_space(1))) unsigned int*)g,
      (__attribute__((address_space(3))) unsigned int*)l, 16, 0, 0);
}

// Raw workgroup barrier with compiler memory fences: does NOT drain vmcnt
// (that is the whole point of the counted-vmcnt pipeline). The "" memory
// clobbers stop LLVM from moving ds_reads / stage issues across phases.
#define BAR() do { asm volatile("" ::: "memory"); \
                   __builtin_amdgcn_s_barrier();  \
                   asm volatile("" ::: "memory"); } while (0)
#define VMCNT6() asm volatile("s_waitcnt vmcnt(6)" ::: "memory")
#define VMCNT0() asm volatile("s_waitcnt vmcnt(0)" ::: "memory")

// Stage this thread's share (2x16B) of one 128x64-bf16 half-tile.
// LDS dest is LINEAR (global_load_lds contract: uniform base + lane*16);
// the read-side XOR swizzle is realized by pre-swizzling the GLOBAL source
// column (see srcC in the kernels), rule #21: linear dest + inv-swz source.
__device__ __forceinline__ void stage2(const unsigned short* src, unsigned short* dst,
                                       int dchunk, int ld) {
  load_lds16(src,                  dst + dchunk);
  load_lds16(src + (size_t)8 * ld, dst + dchunk + 512);
}

// fp32 -> bf16 (RNE), 8 elems/thread: 2x float4 load, 1x 16B store
__global__ __launch_bounds__(256) void cvt_bf16_kernel(
    const float* __restrict__ in, unsigned short* __restrict__ out) {
  size_t i = ((size_t)blockIdx.x * 256 + threadIdx.x) * 8;
  const float4* p = reinterpret_cast<const float4*>(in + i);
  float4 a = p[0], b = p[1];
  us8 o;
  o[0] = f2bf(a.x); o[1] = f2bf(a.y); o[2] = f2bf(a.z); o[3] = f2bf(a.w);
  o[4] = f2bf(b.x); o[5] = f2bf(b.y); o[6] = f2bf(b.z); o[7] = f2bf(b.w);
  *reinterpret_cast<us8*>(out + i) = o;
}

// ---------------------------------------------------------------------------
// Fused gate+up GEMM, 8-phase schedule.
// Tile: 256(M tokens) x 128(N hidden), BK=64. 512 thr = 8 waves (2M x 4N),
// each wave: 128x32 output for BOTH gate and up -> accG/accU[8][2] (128 VGPR).
// LDS 128 KiB: A = 2buf x [2 half x 128 x 64]; B = 2buf x [w1-half | w3-half].
// Swizzle: granule(16B) g -> g ^ (row&7) within each 128B row (conflict-free
// ds_read_b128; staging pre-swizzles the global source column).
// Pipeline: 4 phases/K-tile, 1 half-tile staged per phase, vmcnt(6) once per
// K-tile => 3 half-tiles always in flight across barriers.
// WAR safety (per-buffer region, stage-issue phase > last LDS-read phase):
//   A-lo/A-hi read P0/P1 -> restaged (t+2) at P2/P3
//   B-gate(w1) read P0   -> restaged (t+2) at P1
//   B-up(w3)  read P2    -> restaged (t+1, other buffer) at P0
// ---------------------------------------------------------------------------
__global__ __launch_bounds__(512, 2) void gateup_gemm(
    const unsigned short* __restrict__ xb,   // [NT, DD] bf16
    const unsigned short* __restrict__ w1b,  // [NE, HH, DD] bf16
    const unsigned short* __restrict__ w3b,  // [NE, HH, DD] bf16
    const int* __restrict__ counts,
    unsigned short* __restrict__ h)          // [NT, HH] bf16
{
  extern __shared__ unsigned short lds[];    // 65536 shorts = 128 KiB

  // XCD-contiguous remap: 352 blocks, 44/XCD = exactly one expert per XCD.
  int lin = blockIdx.x + 11 * (blockIdx.y + 4 * blockIdx.z);
  lin = (lin & 7) * 44 + (lin >> 3);
  const int e   = lin / 44;
  const int rem = lin - e * 44;
  const int m0  = (rem / 11) * 256;
  const int n0  = (rem - (rem / 11) * 11) * 128;

  int start = 0;
  for (int i = 0; i < e; ++i) start += counts[i];

  const int tid  = threadIdx.x;
  const int lane = tid & 63;
  const int w    = tid >> 6;
  const int wr   = w >> 2;                 // 0..1  M half (half-tile select)
  const int wc   = w & 3;                  // 0..3  N 32-col group
  const int fm   = lane & 15;
  const int l4   = lane >> 4;
  const int s0   = (l4 ^ (fm & 7)) << 3;   // swizzled granule, ks=0 (shorts)
  const int s1   = s0 ^ 32;                // ks=1
  const int srcR = w * 16 + (lane >> 3);                 // staging row 0..127
  const int srcC = ((lane & 7) ^ (lane >> 3)) << 3;      // pre-swz source col
  const int dchunk = w * 1024 + lane * 8;                // linear LDS dest

  const unsigned short* gA  = xb  + (size_t)(start + m0 + srcR) * DD + srcC;
  const unsigned short* gB1 = w1b + ((size_t)e * HH + n0 + srcR) * DD + srcC;
  const unsigned short* gB3 = w3b + ((size_t)e * HH + n0 + srcR) * DD + srcC;

  unsigned short* ldsA = lds;              // 2 x 16384 shorts
  unsigned short* ldsB = lds + 32768;      // 2 x 16384 shorts (w1-half|w3-half)

  // prologue: tile0 (A-lo,A-hi,B1,B3) + tile1 (B1,A-lo,A-hi). 7 half-tiles.
  stage2(gA,                       ldsA,                 dchunk, DD);
  stage2(gA + (size_t)128 * DD,    ldsA + 8192,          dchunk, DD);
  stage2(gB1,                      ldsB,                 dchunk, DD);
  stage2(gB3,                      ldsB + 8192,          dchunk, DD);
  stage2(gB1 + 64,                 ldsB + 16384,         dchunk, DD);
  stage2(gA + 64,                  ldsA + 16384,         dchunk, DD);
  stage2(gA + (size_t)128 * DD + 64, ldsA + 16384 + 8192, dchunk, DD);
  VMCNT6();          // tile0 complete, tile1 (3 half-tiles) stays in flight
  BAR();

  f32x4 accG[8][2] = {};
  f32x4 accU[8][2] = {};
  const int NTL = DD / 64;   // 32

  for (int t = 0; t < NTL; ++t) {
    const int buf  = (t & 1) << 14;
    const int obuf = buf ^ 16384;
    const unsigned short* At = ldsA + buf + wr * 8192 + fm * 64;
    const unsigned short* Bg = ldsB + buf + (wc * 32 + fm) * 64;
    const unsigned short* Bu = Bg + 8192;
    bf16x8 a0[4][2], a1[4][2], bg[2][2], bu[2][2];

    // ---- P0: (mh0, gate). reads a0(8)+bg(4). stage B3(t+1) -> other buf.
#pragma unroll
    for (int mi = 0; mi < 4; ++mi) {
      a0[mi][0] = *(const bf16x8*)(At + mi * 1024 + s0);
      a0[mi][1] = *(const bf16x8*)(At + mi * 1024 + s1);
    }
#pragma unroll
    for (int nj = 0; nj < 2; ++nj) {
      bg[nj][0] = *(const bf16x8*)(Bg + nj * 1024 + s0);
      bg[nj][1] = *(const bf16x8*)(Bg + nj * 1024 + s1);
    }
    if (t + 1 < NTL) stage2(gB3 + (t + 1) * 64, ldsB + obuf + 8192, dchunk, DD);
    BAR();
    __builtin_amdgcn_s_setprio(1);
#pragma unroll
    for (int mi = 0; mi < 4; ++mi)
#pragma unroll
      for (int nj = 0; nj < 2; ++nj) {
        accG[mi][nj] = MFMA16(a0[mi][0], bg[nj][0], accG[mi][nj]);
        accG[mi][nj] = MFMA16(a0[mi][1], bg[nj][1], accG[mi][nj]);
      }
    __builtin_amdgcn_s_setprio(0);
    BAR();

    // ---- P1: (mh1, gate). reads a1(8). stage B1(t+2) (B1(t) read at P0).
#pragma unroll
    for (int mi = 0; mi < 4; ++mi) {
      a1[mi][0] = *(const bf16x8*)(At + (mi + 4) * 1024 + s0);
      a1[mi][1] = *(const bf16x8*)(At + (mi + 4) * 1024 + s1);
    }
    if (t + 2 < NTL) stage2(gB1 + (t + 2) * 64, ldsB + buf, dchunk, DD);
    BAR();
    __builtin_amdgcn_s_setprio(1);
#pragma unroll
    for (int mi = 0; mi < 4; ++mi)
#pragma unroll
      for (int nj = 0; nj < 2; ++nj) {
        accG[mi + 4][nj] = MFMA16(a1[mi][0], bg[nj][0], accG[mi + 4][nj]);
        accG[mi + 4][nj] = MFMA16(a1[mi][1], bg[nj][1], accG[mi + 4][nj]);
      }
    __builtin_amdgcn_s_setprio(0);
    BAR();

    // ---- P2: (mh0, up). reads bu(4). stage A-lo(t+2) (A reads done P0/P1).
#pragma unroll
    for (int nj = 0; nj < 2; ++nj) {
      bu[nj][0] = *(const bf16x8*)(Bu + nj * 1024 + s0);
      bu[nj][1] = *(const bf16x8*)(Bu + nj * 1024 + s1);
    }
    if (t + 2 < NTL) stage2(gA + (t + 2) * 64, ldsA + buf, dchunk, DD);
    BAR();
    __builtin_amdgcn_s_setprio(1);
#pragma unroll
    for (int mi = 0; mi < 4; ++mi)
#pragma unroll
      for (int nj = 0; nj < 2; ++nj) {
        accU[mi][nj] = MFMA16(a0[mi][0], bu[nj][0], accU[mi][nj]);
        accU[mi][nj] = MFMA16(a0[mi][1], bu[nj][1], accU[mi][nj]);
      }
    __builtin_amdgcn_s_setprio(0);
    BAR();

    // ---- P3: (mh1, up). stage A-hi(t+2); counted vmcnt once per K-tile.
    if (t + 2 < NTL) {
      stage2(gA + (size_t)128 * DD + (t + 2) * 64, ldsA + buf + 8192, dchunk, DD);
      VMCNT6();                     // tile t+1 landed; 3 half-tiles in flight
    } else if (t + 1 < NTL) {
      VMCNT0();                     // drain for the final tile
    }
    BAR();
    __builtin_amdgcn_s_setprio(1);
#pragma unroll
    for (int mi = 0; mi < 4; ++mi)
#pragma unroll
      for (int nj = 0; nj < 2; ++nj) {
        accU[mi + 4][nj] = MFMA16(a1[mi][0], bu[nj][0], accU[mi + 4][nj]);
        accU[mi + 4][nj] = MFMA16(a1[mi][1], bu[nj][1], accU[mi + 4][nj]);
      }
    __builtin_amdgcn_s_setprio(0);
    BAR();
  }

  // epilogue: silu(gate)*up -> bf16. C/D: col=lane&15, row=(lane>>4)*4+r
  const int r0 = l4 * 4;
  const size_t hbase = (size_t)(start + m0 + wr * 128) * HH + n0 + wc * 32 + fm;
#pragma unroll
  for (int mi = 0; mi < 8; ++mi)
#pragma unroll
    for (int nj = 0; nj < 2; ++nj)
#pragma unroll
      for (int r = 0; r < 4; ++r) {
        float gv = accG[mi][nj][r];
        float uv = accU[mi][nj][r];
        float sv = (gv / (1.0f + __expf(-gv))) * uv;
        h[hbase + (size_t)(mi * 16 + r0 + r) * HH + nj * 16] = f2bf(sv);
      }
}

// ---------------------------------------------------------------------------
// Down GEMM: out = h @ w2^T. Tile 256x256, BK=64, 8 waves (2M x 4N), each
// wave 128x64 -> acc[8][4]. Same 8-phase schedule / swizzle as gateup.
// WAR: A-lo/A-hi read P0/P1 -> restage(t+2) P2/P3; B read P0/P2 -> restage
// B-lo(t+2) at P3; B-hi(t+1) targets the other buffer (any phase safe).
// Grid = 256 blocks exactly (1/CU); XCD remap = one expert per XCD.
// ---------------------------------------------------------------------------
__global__ __launch_bounds__(512, 2) void down_gemm(
    const unsigned short* __restrict__ hb,   // [NT, HH] bf16
    const unsigned short* __restrict__ w2b,  // [NE, DD, HH] bf16
    const int* __restrict__ counts,
    float* __restrict__ out)                 // [NT, DD] fp32
{
  extern __shared__ unsigned short lds[];

  int lin = blockIdx.x + 8 * (blockIdx.y + 4 * blockIdx.z);
  lin = (lin & 7) * 32 + (lin >> 3);
  const int e   = lin >> 5;
  const int rem = lin & 31;
  const int m0  = (rem >> 3) * 256;
  const int n0  = (rem & 7) * 256;

  int start = 0;
  for (int i = 0; i < e; ++i) start += counts[i];

  const int tid  = threadIdx.x;
  const int lane = tid & 63;
  const int w    = tid >> 6;
  const int wr   = w >> 2;
  const int wc   = w & 3;
  const int fm   = lane & 15;
  const int l4   = lane >> 4;
  const int s0   = (l4 ^ (fm & 7)) << 3;
  const int s1   = s0 ^ 32;
  const int srcR = w * 16 + (lane >> 3);
  const int srcC = ((lane & 7) ^ (lane >> 3)) << 3;
  const int dchunk = w * 1024 + lane * 8;

  const unsigned short* gA = hb  + (size_t)(start + m0 + srcR) * HH + srcC;
  const unsigned short* gB = w2b + ((size_t)e * DD + n0 + srcR) * HH + srcC;

  unsigned short* ldsA = lds;
  unsigned short* ldsB = lds + 32768;

  // prologue: tile0 full + tile1 {A-lo, A-hi, B-lo}
  stage2(gA,                       ldsA,                 dchunk, HH);
  stage2(gA + (size_t)128 * HH,    ldsA + 8192,          dchunk, HH);
  stage2(gB,                       ldsB,                 dchunk, HH);
  stage2(gB + (size_t)128 * HH,    ldsB + 8192,          dchunk, HH);
  stage2(gA + 64,                  ldsA + 16384,         dchunk, HH);
  stage2(gA + (size_t)128 * HH + 64, ldsA + 16384 + 8192, dchunk, HH);
  stage2(gB + 64,                  ldsB + 16384,         dchunk, HH);
  VMCNT6();
  BAR();

  f32x4 acc[8][4] = {};
  const int NTL = HH / 64;   // 22

  for (int t = 0; t < NTL; ++t) {
    const int buf  = (t & 1) << 14;
    const int obuf = buf ^ 16384;
    const unsigned short* At = ldsA + buf + wr * 8192 + fm * 64;
    const unsigned short* Bt = ldsB + buf + (wc >> 1) * 8192 + ((wc & 1) * 64 + fm) * 64;
    bf16x8 a0[4][2], a1[4][2], b0[2][2], b1[2][2];

    // ---- P0: (mh0, nh0). reads a0(8)+b0(4). stage B-hi(t+1) -> other buf.
#pragma unroll
    for (int mi = 0; mi < 4; ++mi) {
      a0[mi][0] = *(const bf16x8*)(At + mi * 1024 + s0);
      a0[mi][1] = *(const bf16x8*)(At + mi * 1024 + s1);
    }
#pragma unroll
    for (int nj = 0; nj < 2; ++nj) {
      b0[nj][0] = *(const bf16x8*)(Bt + nj * 1024 + s0);
      b0[nj][1] = *(const bf16x8*)(Bt + nj * 1024 + s1);
    }
    if (t + 1 < NTL)
      stage2(gB + (size_t)128 * HH + (t + 1) * 64, ldsB + obuf + 8192, dchunk, HH);
    BAR();
    __builtin_amdgcn_s_setprio(1);
#pragma unroll
    for (int mi = 0; mi < 4; ++mi)
#pragma unroll
      for (int nj = 0; nj < 2; ++nj) {
        acc[mi][nj] = MFMA16(a0[mi][0], b0[nj][0], acc[mi][nj]);
        acc[mi][nj] = MFMA16(a0[mi][1], b0[nj][1], acc[mi][nj]);
      }
    __builtin_amdgcn_s_setprio(0);
    BAR();

    // ---- P1: (mh1, nh0). reads a1(8).
#pragma unroll
    for (int mi = 0; mi < 4; ++mi) {
      a1[mi][0] = *(const bf16x8*)(At + (mi + 4) * 1024 + s0);
      a1[mi][1] = *(const bf16x8*)(At + (mi + 4) * 1024 + s1);
    }
    BAR();
    __builtin_amdgcn_s_setprio(1);
#pragma unroll
    for (int mi = 0; mi < 4; ++mi)
#pragma unroll
      for (int nj = 0; nj < 2; ++nj) {
        acc[mi + 4][nj] = MFMA16(a1[mi][0], b0[nj][0], acc[mi + 4][nj]);
        acc[mi + 4][nj] = MFMA16(a1[mi][1], b0[nj][1], acc[mi + 4][nj]);
      }
    __builtin_amdgcn_s_setprio(0);
    BAR();

    // ---- P2: (mh0, nh1). reads b1(4). stage A-lo(t+2) (A reads done P0/P1).
#pragma unroll
    for (int nj = 0; nj < 2; ++nj) {
      b1[nj][0] = *(const bf16x8*)(Bt + (nj + 2) * 1024 + s0);
      b1[nj][1] = *(const bf16x8*)(Bt + (nj + 2) * 1024 + s1);
    }
    if (t + 2 < NTL) stage2(gA + (t + 2) * 64, ldsA + buf, dchunk, HH);
    BAR();
    __builtin_amdgcn_s_setprio(1);
#pragma unroll
    for (int mi = 0; mi < 4; ++mi)
#pragma unroll
      for (int nj = 0; nj < 2; ++nj) {
        acc[mi][nj + 2] = MFMA16(a0[mi][0], b1[nj][0], acc[mi][nj + 2]);
        acc[mi][nj + 2] = MFMA16(a0[mi][1], b1[nj][1], acc[mi][nj + 2]);
      }
    __builtin_amdgcn_s_setprio(0);
    BAR();

    // ---- P3: (mh1, nh1). stage A-hi(t+2) + B-lo(t+2); counted vmcnt.
    if (t + 2 < NTL) {
      stage2(gA + (size_t)128 * HH + (t + 2) * 64, ldsA + buf + 8192, dchunk, HH);
      stage2(gB + (t + 2) * 64,                    ldsB + buf,        dchunk, HH);
      VMCNT6();
    } else if (t + 1 < NTL) {
      VMCNT0();
    }
    BAR();
    __builtin_amdgcn_s_setprio(1);
#pragma unroll
    for (int mi = 0; mi < 4; ++mi)
#pragma unroll
      for (int nj = 0; nj < 2; ++nj) {
        acc[mi + 4][nj + 2] = MFMA16(a1[mi][0], b1[nj][0], acc[mi + 4][nj + 2]);
        acc[mi + 4][nj + 2] = MFMA16(a1[mi][1], b1[nj][1], acc[mi + 4][nj + 2]);
      }
    __builtin_amdgcn_s_setprio(0);
    BAR();
  }

  const int r0 = l4 * 4;
  const size_t obase = (size_t)(start + m0 + wr * 128) * DD + n0 + wc * 64 + fm;
#pragma unroll
  for (int mi = 0; mi < 8; ++mi)
#pragma unroll
    for (int nj = 0; nj < 4; ++nj)
#pragma unroll
      for (int r = 0; r < 4; ++r)
        out[obase + (size_t)(mi * 16 + r0 + r) * DD + nj * 16] = acc[mi][nj][r];
}

extern "C" void kernel_launch(void* const* d_in, const int* in_sizes, int n_in,
                              void* d_out, int out_size, void* d_ws, size_t ws_size,
                              hipStream_t stream) {
  // setup_inputs order: x, num_tokens_per_expert, w1, w2, w3
  const float* x  = (const float*)d_in[0];
  const int*   cn = (const int*)d_in[1];
  const float* w1 = (const float*)d_in[2];
  const float* w2 = (const float*)d_in[3];
  const float* w3 = (const float*)d_in[4];
  float* out = (float*)d_out;

  // workspace layout (bytes):
  //   [0,            33554432)  xb   (later aliased by w2b)
  //   [33554432,     79691776)  w1b
  //   [79691776,    125829120)  w3b
  //   [125829120,   148897792)  h
  char* ws = (char*)d_ws;
  unsigned short* xb  = (unsigned short*)(ws + 0);
  unsigned short* w1b = (unsigned short*)(ws + 33554432);
  unsigned short* w3b = (unsigned short*)(ws + 79691776);
  unsigned short* hb  = (unsigned short*)(ws + 125829120);
  unsigned short* w2b = (unsigned short*)(ws + 0);  // safe: xb dead after gateup

  static int attr_set = 0;
  if (!attr_set) {
    (void)hipFuncSetAttribute((const void*)gateup_gemm,
                              hipFuncAttributeMaxDynamicSharedMemorySize, 131072);
    (void)hipFuncSetAttribute((const void*)down_gemm,
                              hipFuncAttributeMaxDynamicSharedMemorySize, 131072);
    attr_set = 1;
  }

  cvt_bf16_kernel<<<(NT * DD) / 2048, 256, 0, stream>>>(x, xb);
  cvt_bf16_kernel<<<(NE * HH * DD) / 2048, 256, 0, stream>>>(w1, w1b);
  cvt_bf16_kernel<<<(NE * HH * DD) / 2048, 256, 0, stream>>>(w3, w3b);

  dim3 g1(HH / 128, CAPT / 256, NE);   // (11, 4, 8) = 352 blocks
  gateup_gemm<<<g1, 512, 131072, stream>>>(xb, w1b, w3b, cn, hb);

  cvt_bf16_kernel<<<(NE * DD * HH) / 2048, 256, 0, stream>>>(w2, w2b);

  dim3 g2(DD / 256, CAPT / 256, NE);   // (8, 4, 8) = 256 blocks
  down_gemm<<<g2, 512, 131072, stream>>>(hb, w2b, cn, out);
}